// Round 4
// baseline (227.661 us; speedup 1.0000x reference)
//
#include <hip/hip_runtime.h>

typedef __bf16 bf16x8 __attribute__((ext_vector_type(8)));
typedef unsigned short us8 __attribute__((ext_vector_type(8)));
typedef unsigned short us2 __attribute__((ext_vector_type(2)));
typedef float f32x16 __attribute__((ext_vector_type(16)));

#define N_IMG 32
#define CI 16
#define HH 256
#define WW 256
#define CO 64
#define OHH 254
#define OWW 254
#define RPB 2                 // output rows per block
#define NBLK_H (OHH / RPB)    // 127
#define NBLK (N_IMG * NBLK_H) // 4064 = 8 * 508
#define BLK_PER_XCD (NBLK / 8)

#define XS_W 258              // 256 + 2 zero-pad columns
#define XS_C 24               // ci 16 padded to 24 (48B stride, 16B-aligned b128)
#define WP_SHORTS (CO * 160)
#define WS_NEEDED ((size_t)WP_SHORTS * 2)

__device__ __forceinline__ unsigned short f2bf(float f) {
  union { float f; unsigned u; } v; v.f = f;
  return (unsigned short)((v.u + 0x7FFFu + ((v.u >> 16) & 1u)) >> 16);  // RNE
}

#if defined(__has_builtin)
#if __has_builtin(__builtin_amdgcn_cvt_pk_bf16_f32)
#define HAVE_CVT_PK 1
#endif
#endif

__device__ __forceinline__ us2 cvt2(float a, float b) {
#ifdef HAVE_CVT_PK
  typedef __bf16 bf16x2 __attribute__((ext_vector_type(2)));
  bf16x2 r = __builtin_amdgcn_cvt_pk_bf16_f32(a, b);  // lo=a, hi=b, RNE
  return __builtin_bit_cast(us2, r);
#else
  us2 r; r[0] = f2bf(a); r[1] = f2bf(b); return r;
#endif
}

__device__ __forceinline__ float fast_tanh(float x) {
  float cx = fminf(fmaxf(x, -15.f), 15.f);
  float e = __expf(2.f * cx);
  return (e - 1.f) / (e + 1.f);
}

// ---- prep: weights+bias -> bf16 A-side layout wp[oc][tap*16+ci] (20 KB) ----
__global__ void prep_w(const float* __restrict__ wg, const float* __restrict__ bg,
                       unsigned short* __restrict__ wp) {
  int idx = blockIdx.x * 256 + threadIdx.x;
  if (idx >= WP_SHORTS) return;
  int oc = idx / 160;
  int k = idx - oc * 160;
  int tap = k >> 4, ci = k & 15;
  float v;
  if (tap < 9)      v = wg[oc * 144 + ci * 9 + tap];
  else if (ci == 0) v = bg[oc];
  else              v = 0.f;
  wp[idx] = f2bf(v);
}

// ---- fused conv+min+tanh: one block = 2 output rows of one image ----
// XCD swizzle: blocks with equal (blockIdx&7) [same XCD] take consecutive
// oh-tiles, so the 2 kh-overlap rows shared by vertical neighbors are served
// from that XCD's L2 instead of HBM.
// Implicit GEMM D[oc][pix] = sum_k W[oc][k] X[k][pix], k=tap*16+ci, tap9=bias.
// A-frags loaded from global wp (L1-hot 20KB) per use -> low VGPR, 3 blk/CU.
// C/D: col(lane&31)=pixel, row=(reg&3)+8*(reg>>2)+4*(lane>>5)=oc
//   -> min over oc in-register + one shfl_xor(32).
__global__ __launch_bounds__(256, 3)
void conv_fused(const float* __restrict__ xg, const unsigned short* __restrict__ wp,
                float* __restrict__ out) {
  __shared__ __align__(16) unsigned short xs[(RPB + 2) * XS_W * XS_C];
  const int t = threadIdx.x;
  const int work = (blockIdx.x & 7) * BLK_PER_XCD + (blockIdx.x >> 3);
  const int n = work / NBLK_H;
  const int oh0 = (work - n * NBLK_H) * RPB;

  // ---- stage x rows oh0..oh0+3 (thread t = w); 16 coalesced loads/row ----
  {
    const float* src = xg + (size_t)n * (CI * HH * WW) + t;
#pragma unroll
    for (int r = 0; r < RPB + 2; ++r) {
      float v[16];
#pragma unroll
      for (int j = 0; j < 16; ++j)
        v[j] = src[((size_t)j * HH + (oh0 + r)) * WW];
      union { us8 v8[2]; us2 v2[8]; } pk;
#pragma unroll
      for (int j = 0; j < 8; ++j) pk.v2[j] = cvt2(v[2 * j], v[2 * j + 1]);
      *(us8*)(xs + (r * XS_W + t) * XS_C) = pk.v8[0];      // ds_write_b128
      *(us8*)(xs + (r * XS_W + t) * XS_C + 8) = pk.v8[1];  // ds_write_b128
    }
  }
  if (t < 32 * (RPB + 2)) {     // zero pad columns w=256,257 for all staged rows
    int r = t >> 5, rem = t & 31;
    int w = 256 + (rem >> 4), ci = rem & 15;
    xs[(r * XS_W + w) * XS_C + ci] = 0;
  }
  __syncthreads();

  const int lane = t & 63, wave = t >> 6;
  const int lr = lane & 31, qh = lane >> 5;
  const unsigned short* wpl = wp + lr * 160 + qh * 8;

  us8 onev = {};
  if (qh == 0) onev[0] = 0x3F80;
  const bf16x8 xone = __builtin_bit_cast(bf16x8, onev);

  const int pb = wave * 64;     // this wave's 64-pixel strip

#pragma unroll
  for (int r = 0; r < RPB; ++r) {
    f32x16 acc[2][2];
#pragma unroll
    for (int a = 0; a < 2; ++a)
#pragma unroll
      for (int b = 0; b < 2; ++b)
#pragma unroll
        for (int e = 0; e < 16; ++e) acc[a][b][e] = 0.f;

#pragma unroll
    for (int tap = 0; tap < 9; ++tap) {
      const int kh = tap / 3, kw = tap - kh * 3;
      bf16x8 af0 = __builtin_bit_cast(bf16x8, *(const us8*)(wpl + tap * 16));
      bf16x8 af1 =
          __builtin_bit_cast(bf16x8, *(const us8*)(wpl + 32 * 160 + tap * 16));
#pragma unroll
      for (int nt = 0; nt < 2; ++nt) {
        bf16x8 xf = __builtin_bit_cast(
            bf16x8,
            *(const us8*)(xs + ((r + kh) * XS_W + pb + nt * 32 + lr + kw) * XS_C +
                          qh * 8));
        acc[0][nt] = __builtin_amdgcn_mfma_f32_32x32x16_bf16(af0, xf,
                                                             acc[0][nt], 0, 0, 0);
        acc[1][nt] = __builtin_amdgcn_mfma_f32_32x32x16_bf16(af1, xf,
                                                             acc[1][nt], 0, 0, 0);
      }
    }
    {  // bias tap: B = e_{k=144}
      bf16x8 af0 = __builtin_bit_cast(bf16x8, *(const us8*)(wpl + 9 * 16));
      bf16x8 af1 =
          __builtin_bit_cast(bf16x8, *(const us8*)(wpl + 32 * 160 + 9 * 16));
#pragma unroll
      for (int nt = 0; nt < 2; ++nt) {
        acc[0][nt] = __builtin_amdgcn_mfma_f32_32x32x16_bf16(af0, xone,
                                                             acc[0][nt], 0, 0, 0);
        acc[1][nt] = __builtin_amdgcn_mfma_f32_32x32x16_bf16(af1, xone,
                                                             acc[1][nt], 0, 0, 0);
      }
    }

    float vmin[2];
#pragma unroll
    for (int nt = 0; nt < 2; ++nt) {
      float v = acc[0][nt][0];
#pragma unroll
      for (int e = 1; e < 16; ++e) v = fminf(v, acc[0][nt][e]);
#pragma unroll
      for (int e = 0; e < 16; ++e) v = fminf(v, acc[1][nt][e]);
      v = fminf(v, __shfl_xor(v, 32, 64));
      vmin[nt] = fast_tanh(fast_tanh(v));
    }
    float res = (lane < 32) ? vmin[0] : vmin[1];
    int ow = pb + lane;
    if (ow < OWW) out[((size_t)n * OHH + (oh0 + r)) * OWW + ow] = res;
  }
}

// ================= fallback (round-1 kernel) if ws too small ================
#define WS_K 168
__global__ __launch_bounds__(256, 2)
void conv_min_tanh(const float* __restrict__ xg, const float* __restrict__ wg,
                   const float* __restrict__ bg, float* __restrict__ out) {
  __shared__ __align__(16) unsigned short xs[3 * XS_W * XS_C];
  __shared__ __align__(16) unsigned short ws[CO * WS_K];
  const int t = threadIdx.x;
  const int n = blockIdx.x / OHH;
  const int oh = blockIdx.x % OHH;
#pragma unroll
  for (int i = 0; i < 36; ++i) {
    int f = i * 256 + t;
    int oc = f / 144;
    int r = f - oc * 144;
    int ci = r / 9;
    int tap = r - ci * 9;
    ws[oc * WS_K + tap * 16 + ci] = f2bf(wg[f]);
  }
  if (t < CO) ws[t * WS_K + 144] = f2bf(bg[t]);
  for (int i = t; i < CO * 15; i += 256) {
    int oc = i / 15;
    ws[oc * WS_K + 145 + (i - oc * 15)] = 0;
  }
  {
    const size_t base_n = (size_t)n * CI * HH * WW;
#pragma unroll
    for (int kh = 0; kh < 3; ++kh) {
#pragma unroll
      for (int half = 0; half < 2; ++half) {
        float v[8];
#pragma unroll
        for (int j = 0; j < 8; ++j) {
          int ci = half * 8 + j;
          v[j] = xg[base_n + ((size_t)ci * HH + (oh + kh)) * WW + t];
        }
        us8 pk;
#pragma unroll
        for (int j = 0; j < 8; ++j) pk[j] = f2bf(v[j]);
        *(us8*)(xs + (kh * XS_W + t) * XS_C + half * 8) = pk;
      }
    }
  }
  if (t < 96) {
    int kh = t >> 5;
    int rem = t & 31;
    int w = 256 + (rem >> 4);
    int ci = rem & 15;
    xs[(kh * XS_W + w) * XS_C + ci] = 0;
  }
  __syncthreads();
  const int lane = t & 63, wave = t >> 6;
  const int lr = lane & 31, qh = lane >> 5;
  bf16x8 afrag[2][10];
#pragma unroll
  for (int mt = 0; mt < 2; ++mt) {
    const unsigned short* wq = ws + (mt * 32 + lr) * WS_K + qh * 8;
#pragma unroll
    for (int tap = 0; tap < 10; ++tap)
      afrag[mt][tap] = __builtin_bit_cast(bf16x8, *(const us8*)(wq + tap * 16));
  }
  f32x16 acc[2][2];
#pragma unroll
  for (int a = 0; a < 2; ++a)
#pragma unroll
    for (int b = 0; b < 2; ++b)
#pragma unroll
      for (int e = 0; e < 16; ++e) acc[a][b][e] = 0.f;
  const unsigned short* xq = xs + (wave * 64 + lr) * XS_C + qh * 8;
#pragma unroll
  for (int tap = 0; tap < 9; ++tap) {
    const int kh = tap / 3, kw = tap - kh * 3;
#pragma unroll
    for (int nt = 0; nt < 2; ++nt) {
      bf16x8 xf = __builtin_bit_cast(
          bf16x8, *(const us8*)(xq + (kh * XS_W + nt * 32 + kw) * XS_C));
      acc[0][nt] = __builtin_amdgcn_mfma_f32_32x32x16_bf16(afrag[0][tap], xf,
                                                           acc[0][nt], 0, 0, 0);
      acc[1][nt] = __builtin_amdgcn_mfma_f32_32x32x16_bf16(afrag[1][tap], xf,
                                                           acc[1][nt], 0, 0, 0);
    }
  }
  {
    us8 one = {};
    if (qh == 0) one[0] = 0x3F80;
    bf16x8 xone = __builtin_bit_cast(bf16x8, one);
#pragma unroll
    for (int nt = 0; nt < 2; ++nt) {
      acc[0][nt] = __builtin_amdgcn_mfma_f32_32x32x16_bf16(afrag[0][9], xone,
                                                           acc[0][nt], 0, 0, 0);
      acc[1][nt] = __builtin_amdgcn_mfma_f32_32x32x16_bf16(afrag[1][9], xone,
                                                           acc[1][nt], 0, 0, 0);
    }
  }
  float vmin[2];
#pragma unroll
  for (int nt = 0; nt < 2; ++nt) {
    float v = acc[0][nt][0];
#pragma unroll
    for (int e = 1; e < 16; ++e) v = fminf(v, acc[0][nt][e]);
#pragma unroll
    for (int e = 0; e < 16; ++e) v = fminf(v, acc[1][nt][e]);
    v = fminf(v, __shfl_xor(v, 32, 64));
    vmin[nt] = fast_tanh(fast_tanh(v));
  }
  float res = (lane < 32) ? vmin[0] : vmin[1];
  int ow = wave * 64 + lane;
  if (ow < OWW) out[((size_t)n * OHH + oh) * OWW + ow] = res;
}

extern "C" void kernel_launch(void* const* d_in, const int* in_sizes, int n_in,
                              void* d_out, int out_size, void* d_ws, size_t ws_size,
                              hipStream_t stream) {
  const float* x = (const float*)d_in[0];
  const float* w = (const float*)d_in[1];
  const float* b = (const float*)d_in[2];
  float* out = (float*)d_out;
  if (ws_size >= WS_NEEDED) {
    unsigned short* wp = (unsigned short*)d_ws;
    prep_w<<<dim3((WP_SHORTS + 255) / 256), dim3(256), 0, stream>>>(w, b, wp);
    conv_fused<<<dim3(NBLK), dim3(256), 0, stream>>>(x, wp, out);
  } else {
    conv_min_tanh<<<dim3(N_IMG * OHH), dim3(256), 0, stream>>>(x, w, b, out);
  }
}

// Round 5
// 213.290 us; speedup vs baseline: 1.0674x; 1.0674x over previous
//
#include <hip/hip_runtime.h>

typedef __bf16 bf16x8 __attribute__((ext_vector_type(8)));
typedef unsigned short us8 __attribute__((ext_vector_type(8)));
typedef unsigned short us2 __attribute__((ext_vector_type(2)));
typedef float f32x16 __attribute__((ext_vector_type(16)));

#define N_IMG 32
#define CI 16
#define HH 256
#define WW 256
#define CO 64
#define OHH 254
#define OWW 254
#define RPB 2                 // output rows per block
#define NBLK_H (OHH / RPB)    // 127
#define NBLK (N_IMG * NBLK_H) // 4064

#define XS_W 258              // 256 + 2 zero-pad columns
#define XS_C 24               // ci 16 padded to 24 (48B stride, 16B-aligned b128,
                              //   conflict-free: 12w mod 32 covers all banks per 8 w)
#define WP_SHORTS (CO * 160)
#define WS_NEEDED ((size_t)WP_SHORTS * 2)

__device__ __forceinline__ unsigned short f2bf(float f) {
  union { float f; unsigned u; } v; v.f = f;
  return (unsigned short)((v.u + 0x7FFFu + ((v.u >> 16) & 1u)) >> 16);  // RNE
}

#if defined(__has_builtin)
#if __has_builtin(__builtin_amdgcn_cvt_pk_bf16_f32)
#define HAVE_CVT_PK 1
#endif
#endif

__device__ __forceinline__ us2 cvt2(float a, float b) {
#ifdef HAVE_CVT_PK
  typedef __bf16 bf16x2 __attribute__((ext_vector_type(2)));
  bf16x2 r = __builtin_amdgcn_cvt_pk_bf16_f32(a, b);  // lo=a, hi=b, RNE
  return __builtin_bit_cast(us2, r);
#else
  us2 r; r[0] = f2bf(a); r[1] = f2bf(b); return r;
#endif
}

__device__ __forceinline__ float fast_tanh(float x) {
  float cx = fminf(fmaxf(x, -15.f), 15.f);
  float e = __expf(2.f * cx);
  return (e - 1.f) / (e + 1.f);
}

// ---- prep: weights+bias -> bf16 A-side layout wp[oc][tap*16+ci] (20 KB) ----
__global__ void prep_w(const float* __restrict__ wg, const float* __restrict__ bg,
                       unsigned short* __restrict__ wp) {
  int idx = blockIdx.x * 256 + threadIdx.x;
  if (idx >= WP_SHORTS) return;
  int oc = idx / 160;
  int k = idx - oc * 160;
  int tap = k >> 4, ci = k & 15;
  float v;
  if (tap < 9)      v = wg[oc * 144 + ci * 9 + tap];
  else if (ci == 0) v = bg[oc];
  else              v = 0.f;
  wp[idx] = f2bf(v);
}

// ---- fused conv+min+tanh: one block = 2 output rows of one image ----
// Implicit GEMM D[oc][pix] = sum_k W[oc][k] X[k][pix], k=tap*16+ci, tap9=bias.
// Staging: ALL 64 fp32 loads (4 rows x 16 ci) issued as one batch into
// v[4][16] (one L3 latency amortized over 64 outstanding loads), then
// cvt_pk -> LDS [row][w][ci] via conflict-free ds_write_b128.
// A-frags preloaded ONCE into 80 VGPRs after the barrier (L1/L2-hot 20KB wp).
// C/D: col(lane&31)=pixel, row=(reg&3)+8*(reg>>2)+4*(lane>>5)=oc
//   -> min over oc in-register + one shfl_xor(32).
__global__ __launch_bounds__(256, 3)
void conv_fused(const float* __restrict__ xg, const unsigned short* __restrict__ wp,
                float* __restrict__ out) {
  __shared__ __align__(16) unsigned short xs[(RPB + 2) * XS_W * XS_C];
  const int t = threadIdx.x;
  const int n = blockIdx.x / NBLK_H;
  const int oh0 = (blockIdx.x - n * NBLK_H) * RPB;

  // ---- stage x rows oh0..oh0+3 (thread t = w): batch-load then convert ----
  {
    const float* src = xg + (size_t)n * (CI * HH * WW) + t;
    float v[RPB + 2][16];
#pragma unroll
    for (int r = 0; r < RPB + 2; ++r)
#pragma unroll
      for (int j = 0; j < 16; ++j)
        v[r][j] = src[((size_t)j * HH + (oh0 + r)) * WW];
#pragma unroll
    for (int r = 0; r < RPB + 2; ++r) {
      union { us8 v8[2]; us2 v2[8]; } pk;
#pragma unroll
      for (int j = 0; j < 8; ++j) pk.v2[j] = cvt2(v[r][2 * j], v[r][2 * j + 1]);
      *(us8*)(xs + (r * XS_W + t) * XS_C) = pk.v8[0];      // ds_write_b128
      *(us8*)(xs + (r * XS_W + t) * XS_C + 8) = pk.v8[1];  // ds_write_b128
    }
  }
  if (t < 32 * (RPB + 2)) {     // zero pad columns w=256,257 for all staged rows
    int r = t >> 5, rem = t & 31;
    int w = 256 + (rem >> 4), ci = rem & 15;
    xs[(r * XS_W + w) * XS_C + ci] = 0;
  }
  __syncthreads();

  const int lane = t & 63, wave = t >> 6;
  const int lr = lane & 31, qh = lane >> 5;

  // preload A-frags ONCE into registers (2 mt x 10 taps x 4 VGPR = 80 VGPRs)
  const unsigned short* wpl = wp + lr * 160 + qh * 8;
  bf16x8 afrag[2][10];
#pragma unroll
  for (int mt = 0; mt < 2; ++mt)
#pragma unroll
    for (int tap = 0; tap < 10; ++tap)
      afrag[mt][tap] =
          __builtin_bit_cast(bf16x8, *(const us8*)(wpl + mt * 32 * 160 + tap * 16));

  us8 onev = {};
  if (qh == 0) onev[0] = 0x3F80;
  const bf16x8 xone = __builtin_bit_cast(bf16x8, onev);

  const int pb = wave * 64;     // this wave's 64-pixel strip

#pragma unroll
  for (int r = 0; r < RPB; ++r) {
    f32x16 acc[2][2];
#pragma unroll
    for (int a = 0; a < 2; ++a)
#pragma unroll
      for (int b = 0; b < 2; ++b)
#pragma unroll
        for (int e = 0; e < 16; ++e) acc[a][b][e] = 0.f;

#pragma unroll
    for (int tap = 0; tap < 9; ++tap) {
      const int kh = tap / 3, kw = tap - kh * 3;
#pragma unroll
      for (int nt = 0; nt < 2; ++nt) {
        bf16x8 xf = __builtin_bit_cast(
            bf16x8,
            *(const us8*)(xs + ((r + kh) * XS_W + pb + nt * 32 + lr + kw) * XS_C +
                          qh * 8));
        acc[0][nt] = __builtin_amdgcn_mfma_f32_32x32x16_bf16(afrag[0][tap], xf,
                                                             acc[0][nt], 0, 0, 0);
        acc[1][nt] = __builtin_amdgcn_mfma_f32_32x32x16_bf16(afrag[1][tap], xf,
                                                             acc[1][nt], 0, 0, 0);
      }
    }
#pragma unroll
    for (int nt = 0; nt < 2; ++nt) {  // bias tap: B = e_{k=144}
      acc[0][nt] = __builtin_amdgcn_mfma_f32_32x32x16_bf16(afrag[0][9], xone,
                                                           acc[0][nt], 0, 0, 0);
      acc[1][nt] = __builtin_amdgcn_mfma_f32_32x32x16_bf16(afrag[1][9], xone,
                                                           acc[1][nt], 0, 0, 0);
    }

    float vmin[2];
#pragma unroll
    for (int nt = 0; nt < 2; ++nt) {
      float v = acc[0][nt][0];
#pragma unroll
      for (int e = 1; e < 16; ++e) v = fminf(v, acc[0][nt][e]);
#pragma unroll
      for (int e = 0; e < 16; ++e) v = fminf(v, acc[1][nt][e]);
      v = fminf(v, __shfl_xor(v, 32, 64));
      vmin[nt] = fast_tanh(fast_tanh(v));
    }
    float res = (lane < 32) ? vmin[0] : vmin[1];
    int ow = pb + lane;
    if (ow < OWW) out[((size_t)n * OHH + (oh0 + r)) * OWW + ow] = res;
  }
}

// ================= fallback (round-1 kernel) if ws too small ================
#define WS_K 168
__global__ __launch_bounds__(256, 2)
void conv_min_tanh(const float* __restrict__ xg, const float* __restrict__ wg,
                   const float* __restrict__ bg, float* __restrict__ out) {
  __shared__ __align__(16) unsigned short xs[3 * XS_W * XS_C];
  __shared__ __align__(16) unsigned short ws[CO * WS_K];
  const int t = threadIdx.x;
  const int n = blockIdx.x / OHH;
  const int oh = blockIdx.x % OHH;
#pragma unroll
  for (int i = 0; i < 36; ++i) {
    int f = i * 256 + t;
    int oc = f / 144;
    int r = f - oc * 144;
    int ci = r / 9;
    int tap = r - ci * 9;
    ws[oc * WS_K + tap * 16 + ci] = f2bf(wg[f]);
  }
  if (t < CO) ws[t * WS_K + 144] = f2bf(bg[t]);
  for (int i = t; i < CO * 15; i += 256) {
    int oc = i / 15;
    ws[oc * WS_K + 145 + (i - oc * 15)] = 0;
  }
  {
    const size_t base_n = (size_t)n * CI * HH * WW;
#pragma unroll
    for (int kh = 0; kh < 3; ++kh) {
#pragma unroll
      for (int half = 0; half < 2; ++half) {
        float v[8];
#pragma unroll
        for (int j = 0; j < 8; ++j) {
          int ci = half * 8 + j;
          v[j] = xg[base_n + ((size_t)ci * HH + (oh + kh)) * WW + t];
        }
        us8 pk;
#pragma unroll
        for (int j = 0; j < 8; ++j) pk[j] = f2bf(v[j]);
        *(us8*)(xs + (kh * XS_W + t) * XS_C + half * 8) = pk;
      }
    }
  }
  if (t < 96) {
    int kh = t >> 5;
    int rem = t & 31;
    int w = 256 + (rem >> 4);
    int ci = rem & 15;
    xs[(kh * XS_W + w) * XS_C + ci] = 0;
  }
  __syncthreads();
  const int lane = t & 63, wave = t >> 6;
  const int lr = lane & 31, qh = lane >> 5;
  bf16x8 afrag[2][10];
#pragma unroll
  for (int mt = 0; mt < 2; ++mt) {
    const unsigned short* wq = ws + (mt * 32 + lr) * WS_K + qh * 8;
#pragma unroll
    for (int tap = 0; tap < 10; ++tap)
      afrag[mt][tap] = __builtin_bit_cast(bf16x8, *(const us8*)(wq + tap * 16));
  }
  f32x16 acc[2][2];
#pragma unroll
  for (int a = 0; a < 2; ++a)
#pragma unroll
    for (int b = 0; b < 2; ++b)
#pragma unroll
      for (int e = 0; e < 16; ++e) acc[a][b][e] = 0.f;
  const unsigned short* xq = xs + (wave * 64 + lr) * XS_C + qh * 8;
#pragma unroll
  for (int tap = 0; tap < 9; ++tap) {
    const int kh = tap / 3, kw = tap - kh * 3;
#pragma unroll
    for (int nt = 0; nt < 2; ++nt) {
      bf16x8 xf = __builtin_bit_cast(
          bf16x8, *(const us8*)(xq + (kh * XS_W + nt * 32 + kw) * XS_C));
      acc[0][nt] = __builtin_amdgcn_mfma_f32_32x32x16_bf16(afrag[0][tap], xf,
                                                           acc[0][nt], 0, 0, 0);
      acc[1][nt] = __builtin_amdgcn_mfma_f32_32x32x16_bf16(afrag[1][tap], xf,
                                                           acc[1][nt], 0, 0, 0);
    }
  }
  {
    us8 one = {};
    if (qh == 0) one[0] = 0x3F80;
    bf16x8 xone = __builtin_bit_cast(bf16x8, one);
#pragma unroll
    for (int nt = 0; nt < 2; ++nt) {
      acc[0][nt] = __builtin_amdgcn_mfma_f32_32x32x16_bf16(afrag[0][9], xone,
                                                           acc[0][nt], 0, 0, 0);
      acc[1][nt] = __builtin_amdgcn_mfma_f32_32x32x16_bf16(afrag[1][9], xone,
                                                           acc[1][nt], 0, 0, 0);
    }
  }
  float vmin[2];
#pragma unroll
  for (int nt = 0; nt < 2; ++nt) {
    float v = acc[0][nt][0];
#pragma unroll
    for (int e = 1; e < 16; ++e) v = fminf(v, acc[0][nt][e]);
#pragma unroll
    for (int e = 0; e < 16; ++e) v = fminf(v, acc[1][nt][e]);
    v = fminf(v, __shfl_xor(v, 32, 64));
    vmin[nt] = fast_tanh(fast_tanh(v));
  }
  float res = (lane < 32) ? vmin[0] : vmin[1];
  int ow = wave * 64 + lane;
  if (ow < OWW) out[((size_t)n * OHH + oh) * OWW + ow] = res;
}

extern "C" void kernel_launch(void* const* d_in, const int* in_sizes, int n_in,
                              void* d_out, int out_size, void* d_ws, size_t ws_size,
                              hipStream_t stream) {
  const float* x = (const float*)d_in[0];
  const float* w = (const float*)d_in[1];
  const float* b = (const float*)d_in[2];
  float* out = (float*)d_out;
  if (ws_size >= WS_NEEDED) {
    unsigned short* wp = (unsigned short*)d_ws;
    prep_w<<<dim3((WP_SHORTS + 255) / 256), dim3(256), 0, stream>>>(w, b, wp);
    conv_fused<<<dim3(NBLK), dim3(256), 0, stream>>>(x, wp, out);
  } else {
    conv_min_tanh<<<dim3(N_IMG * OHH), dim3(256), 0, stream>>>(x, w, b, out);
  }
}